// Round 12
// baseline (156.334 us; speedup 1.0000x reference)
//
#include <hip/hip_runtime.h>
#include <cstdint>

#define BN 9216      // N = H*W = 96*96
#define NB 2         // batch
#define CIN 64       // C
#define DI 32        // inter
#define MC 4         // m-chunks (cross-block m-split)
#define NCHUNK 288   // BN/32 query chunks
#define LOG2E 1.4426950408889634f

typedef __attribute__((ext_vector_type(4))) float f32x4;
typedef __attribute__((ext_vector_type(8))) __bf16 bf16x8;
typedef __attribute__((ext_vector_type(2))) unsigned int u32x2;

// fp32 -> bf16 bits, round-to-nearest-even
__device__ __forceinline__ unsigned short f2bf(float f) {
    unsigned int u = __builtin_bit_cast(unsigned int, f);
    u += 0x7FFFu + ((u >> 16) & 1u);
    return (unsigned short)(u >> 16);
}
__device__ __forceinline__ unsigned int packbf(float lo, float hi) {
    return (unsigned int)f2bf(lo) | ((unsigned int)f2bf(hi) << 16);
}

// hardware exp2 (v_exp_f32 IS 2^x)
__device__ __forceinline__ float exp2_hw(float x) {
    float r;
    asm("v_exp_f32 %0, %1" : "=v"(r) : "v"(x));
    return r;
}

// ---------------------------------------------------------------------------
// Kernel 1: fused conv1x1 (phi/theta/g in one pass, x loaded once/thread).
// grid = (BN/256, 8, NB); block = 256; og = 4-channel output group.
//   qT/kT: [B][N][32] bf16 (phi scaled by LOG2E); vv: [B][32][N] bf16 natural
// ---------------------------------------------------------------------------
__global__ __launch_bounds__(256) void qkv_kernel(
    const float* __restrict__ x,
    const float* __restrict__ g_w, const float* __restrict__ g_b,
    const float* __restrict__ th_w, const float* __restrict__ th_b,
    const float* __restrict__ ph_w, const float* __restrict__ ph_b,
    unsigned short* __restrict__ qT, unsigned short* __restrict__ kT,
    unsigned short* __restrict__ vv)
{
    __shared__ float wsh[3 * 4 * CIN];   // [conv][o][c]; 0=phi,1=theta,2=g
    __shared__ float bsh[12];
    const int og = blockIdx.y;           // 8 groups of 4 output channels
    const int b = blockIdx.z;
    const int tid = threadIdx.x;
    if (tid < 4 * CIN) {                 // 256 threads, 256 entries per conv
        const int o = tid / CIN, c = tid % CIN;
        wsh[0 * 256 + tid] = ph_w[(size_t)(og * 4 + o) * CIN + c] * LOG2E;
        wsh[1 * 256 + tid] = th_w[(size_t)(og * 4 + o) * CIN + c];
        wsh[2 * 256 + tid] = g_w [(size_t)(og * 4 + o) * CIN + c];
    }
    if (tid < 4) {
        bsh[tid]     = ph_b[og * 4 + tid] * LOG2E;
        bsh[4 + tid] = th_b[og * 4 + tid];
        bsh[8 + tid] = g_b [og * 4 + tid];
    }
    __syncthreads();

    const int n = blockIdx.x * 256 + tid;
    const float* xp = x + (size_t)b * CIN * BN + n;

    float aq[4], ak[4], av[4];
#pragma unroll
    for (int o = 0; o < 4; ++o) {
        aq[o] = bsh[o]; ak[o] = bsh[4 + o]; av[o] = bsh[8 + o];
    }
    for (int c0 = 0; c0 < CIN; c0 += 16) {     // 16 loads in flight per batch
        float xv[16];
#pragma unroll
        for (int u = 0; u < 16; ++u) xv[u] = xp[(size_t)(c0 + u) * BN];
#pragma unroll
        for (int u = 0; u < 16; ++u) {
#pragma unroll
            for (int o = 0; o < 4; ++o) {
                aq[o] += wsh[0 * 256 + o * CIN + c0 + u] * xv[u];
                ak[o] += wsh[1 * 256 + o * CIN + c0 + u] * xv[u];
                av[o] += wsh[2 * 256 + o * CIN + c0 + u] * xv[u];
            }
        }
    }

    {
        unsigned short* qp = qT + ((size_t)b * BN + n) * DI + og * 4;
        u32x2 tq = {packbf(aq[0], aq[1]), packbf(aq[2], aq[3])};
        *(u32x2*)qp = tq;
        unsigned short* kp = kT + ((size_t)b * BN + n) * DI + og * 4;
        u32x2 tk = {packbf(ak[0], ak[1]), packbf(ak[2], ak[3])};
        *(u32x2*)kp = tk;
    }
    {
        unsigned short* vp = vv + (size_t)b * DI * BN + n;   // natural layout
#pragma unroll
        for (int o = 0; o < 4; ++o) vp[(size_t)(og * 4 + o) * BN] = f2bf(av[o]);
    }
}

// ---------------------------------------------------------------------------
// Kernel 2: flash-attention partial, fixed-M softmax (M=0), K-row-permuted
// QK^T + full-K=32 PV, software-pipelined loads. grid = (NCHUNK, MC, NB),
// block = 256; 4 waves split the mc*2304..+2304 m-range (step 128, 18 iters).
// Lane q loads K rows m0+sig(q), +4 (sig = 8*(q>>2)+(q&3)) so the 8 exp'd P
// values are exactly PV's mfma_16x16x32 B-operand. Partials: plain sums.
// ---------------------------------------------------------------------------
__global__ __launch_bounds__(256) void attn_partial(
    const unsigned short* __restrict__ qT, const unsigned short* __restrict__ kT,
    const unsigned short* __restrict__ vv,
    float* __restrict__ pacc, float* __restrict__ pl)
{
    __shared__ float red_l[4][2][16];
    __shared__ float red_acc[4][2][512];   // [wave][tile][i*16+q]

    const int b  = blockIdx.z;
    const int mc = blockIdx.y;
    const int nc = blockIdx.x;
    const int n0 = nc * 32;
    const int tid = threadIdx.x;
    const int w = tid >> 6;
    const int lane = tid & 63;
    const int h = lane >> 4;
    const int q = lane & 15;
    const int sig = 8 * (q >> 2) + (q & 3);   // K-row permutation

    const unsigned short* qTb = qT + (size_t)b * BN * DI;
    const unsigned short* kTb = kT + (size_t)b * BN * DI;
    const unsigned short* vb  = vv + (size_t)b * DI * BN;

    bf16x8 qfA = *(const bf16x8*)(qTb + ((size_t)(n0 + q)) * DI + 8 * h);
    bf16x8 qfB = *(const bf16x8*)(qTb + ((size_t)(n0 + 16 + q)) * DI + 8 * h);
    const f32x4 zero = {0.f, 0.f, 0.f, 0.f};
    f32x4 a0A = zero, a1A = zero, a0B = zero, a1B = zero;
    float lA = 0.f, lB = 0.f;

    const unsigned short* krow = kTb + (size_t)sig * DI + 8 * h;  // + m0*DI
    const unsigned short* vrow0 = vb + (size_t)q * BN + 8 * h;    // + m0
    const unsigned short* vrow1 = vb + (size_t)(16 + q) * BN + 8 * h;

    int m0 = mc * 2304 + w * 32;

#define LD_K0(m) (*(const bf16x8*)(krow + (size_t)(m) * DI))
#define LD_K1(m) (*(const bf16x8*)(krow + (size_t)((m) + 4) * DI))
#define LD_V0(m) (*(const bf16x8*)(vrow0 + (m)))
#define LD_V1(m) (*(const bf16x8*)(vrow1 + (m)))

    bf16x8 ck0 = LD_K0(m0), ck1 = LD_K1(m0), cv0 = LD_V0(m0), cv1 = LD_V1(m0);

    auto compute = [&](bf16x8 k0, bf16x8 k1, bf16x8 v0, bf16x8 v1) {
        f32x4 s0A = __builtin_amdgcn_mfma_f32_16x16x32_bf16(k0, qfA, zero, 0, 0, 0);
        f32x4 s1A = __builtin_amdgcn_mfma_f32_16x16x32_bf16(k1, qfA, zero, 0, 0, 0);
        f32x4 s0B = __builtin_amdgcn_mfma_f32_16x16x32_bf16(k0, qfB, zero, 0, 0, 0);
        f32x4 s1B = __builtin_amdgcn_mfma_f32_16x16x32_bf16(k1, qfB, zero, 0, 0, 0);
        // ---- tile A ----
        {
            float p0 = exp2_hw(s0A[0]), p1 = exp2_hw(s0A[1]);
            float p2 = exp2_hw(s0A[2]), p3 = exp2_hw(s0A[3]);
            float p4 = exp2_hw(s1A[0]), p5 = exp2_hw(s1A[1]);
            float p6 = exp2_hw(s1A[2]), p7 = exp2_hw(s1A[3]);
            lA += ((p0 + p1) + (p2 + p3)) + ((p4 + p5) + (p6 + p7));
            bf16x8 pf = {(__bf16)p0, (__bf16)p1, (__bf16)p2, (__bf16)p3,
                         (__bf16)p4, (__bf16)p5, (__bf16)p6, (__bf16)p7};
            a0A = __builtin_amdgcn_mfma_f32_16x16x32_bf16(v0, pf, a0A, 0, 0, 0);
            a1A = __builtin_amdgcn_mfma_f32_16x16x32_bf16(v1, pf, a1A, 0, 0, 0);
        }
        // ---- tile B ----
        {
            float p0 = exp2_hw(s0B[0]), p1 = exp2_hw(s0B[1]);
            float p2 = exp2_hw(s0B[2]), p3 = exp2_hw(s0B[3]);
            float p4 = exp2_hw(s1B[0]), p5 = exp2_hw(s1B[1]);
            float p6 = exp2_hw(s1B[2]), p7 = exp2_hw(s1B[3]);
            lB += ((p0 + p1) + (p2 + p3)) + ((p4 + p5) + (p6 + p7));
            bf16x8 pf = {(__bf16)p0, (__bf16)p1, (__bf16)p2, (__bf16)p3,
                         (__bf16)p4, (__bf16)p5, (__bf16)p6, (__bf16)p7};
            a0B = __builtin_amdgcn_mfma_f32_16x16x32_bf16(v0, pf, a0B, 0, 0, 0);
            a1B = __builtin_amdgcn_mfma_f32_16x16x32_bf16(v1, pf, a1B, 0, 0, 0);
        }
    };

#pragma unroll 1
    for (int it = 0; it < 17; ++it) {          // pipelined: prefetch next tile
        const int mn = m0 + 128;
        bf16x8 nk0 = LD_K0(mn), nk1 = LD_K1(mn);
        bf16x8 nv0 = LD_V0(mn), nv1 = LD_V1(mn);
        compute(ck0, ck1, cv0, cv1);
        ck0 = nk0; ck1 = nk1; cv0 = nv0; cv1 = nv1;
        m0 = mn;
    }
    compute(ck0, ck1, cv0, cv1);               // peeled last iteration

#undef LD_K0
#undef LD_K1
#undef LD_V0
#undef LD_V1

    // per-lane partial l -> per-q partial (sum over h-groups)
    lA += __shfl_xor(lA, 16, 64); lA += __shfl_xor(lA, 32, 64);
    lB += __shfl_xor(lB, 16, 64); lB += __shfl_xor(lB, 32, 64);

    if (lane < 16) { red_l[w][0][lane] = lA; red_l[w][1][lane] = lB; }

    // park acc in LDS (plain — fixed M across all partials)
#pragma unroll
    for (int t = 0; t < 4; ++t) {
        red_acc[w][0][(4 * h + t) * 16 + q]      = a0A[t];
        red_acc[w][0][(16 + 4 * h + t) * 16 + q] = a1A[t];
        red_acc[w][1][(4 * h + t) * 16 + q]      = a0B[t];
        red_acc[w][1][(16 + 4 * h + t) * 16 + q] = a1B[t];
    }
    __syncthreads();

    // write partial acc: thread t -> n' = t&31 (tile tt, col qq), 4 i's
    {
        const int np = tid & 31;
        const int ig = tid >> 5;
        const int tt = np >> 4, qq = np & 15;
        const size_t pbase = (((size_t)b * MC + mc) * NCHUNK + nc) * 1024;
#pragma unroll
        for (int ii = 0; ii < 4; ++ii) {
            const int i = ig * 4 + ii;
            float ysum = red_acc[0][tt][i * 16 + qq] + red_acc[1][tt][i * 16 + qq]
                       + red_acc[2][tt][i * 16 + qq] + red_acc[3][tt][i * 16 + qq];
            pacc[pbase + (size_t)i * 32 + np] = ysum;
        }
        if (tid < 32) {
            float L = red_l[0][tt][qq] + red_l[1][tt][qq]
                    + red_l[2][tt][qq] + red_l[3][tt][qq];
            pl[(((size_t)b * MC + mc) * NCHUNK + nc) * 32 + np] = L;
        }
    }
}

// ---------------------------------------------------------------------------
// Kernel 3: combine MC partials (plain sums) -> y, then fused outconv +
// residual. grid = (NCHUNK*2, NB), block = 256; each block: 16 n columns.
// ---------------------------------------------------------------------------
__global__ __launch_bounds__(256) void combine_outconv(
    const float* __restrict__ pacc, const float* __restrict__ pl,
    const float* __restrict__ Ww, const float* __restrict__ Wb,
    const float* __restrict__ x, float* __restrict__ out)
{
    __shared__ float sl[MC * 16];         // [mc][n16]
    __shared__ float ysh[32 * 17];        // y[i][n16], pitch 17
    __shared__ float WwT[32 * 65];        // WwT[i][o], pitch 65
    __shared__ float swb[64];

    const int b    = blockIdx.y;
    const int nc2  = blockIdx.x;          // 16-column block index
    const int nc   = nc2 >> 1;
    const int half = nc2 & 1;
    const int tid  = threadIdx.x;
    const int n16  = tid & 15;
    const int grp  = tid >> 4;            // 0..15
    const int np   = half * 16 + n16;     // column within the 32-n chunk

    // stage pl (64 floats), WwT (2048), Wb (64)
    {
        if (tid < MC * 16) {
            const int mc = tid >> 4, j = tid & 15;
            sl[tid] = pl[(((size_t)b * MC + mc) * NCHUNK + nc) * 32
                         + half * 16 + j];
        }
#pragma unroll
        for (int e = tid; e < 2048; e += 256)
            WwT[(e & 31) * 65 + (e >> 5)] = Ww[e];
        if (tid < 64) swb[tid] = Wb[tid];
    }

    // residual loads issued early (4 channels per thread: o = grp*4..+3)
    float xr[4];
    const float* xp = x + ((size_t)b * CIN + grp * 4) * BN + nc2 * 16 + n16;
#pragma unroll
    for (int oo = 0; oo < 4; ++oo) xr[oo] = xp[(size_t)oo * BN];

    __syncthreads();

    // combine: thread handles i = grp*2, grp*2+1 at column n16
    {
        float L = 0.f;
#pragma unroll
        for (int mc2 = 0; mc2 < MC; ++mc2) L += sl[mc2 * 16 + n16];
        const float inv = 1.0f / L;

        const size_t pb0 = (((size_t)b * MC) * NCHUNK + nc) * 1024;
#pragma unroll
        for (int ii = 0; ii < 2; ++ii) {
            const int i = grp * 2 + ii;
            float y = 0.f;
#pragma unroll
            for (int mc2 = 0; mc2 < MC; ++mc2)
                y += pacc[pb0 + (size_t)mc2 * NCHUNK * 1024 + (size_t)i * 32 + np];
            ysh[i * 17 + n16] = y * inv;
        }
    }
    __syncthreads();

    // outconv: thread handles 4 output channels o = grp*4+oo at column n16
    {
        float acc[4];
#pragma unroll
        for (int oo = 0; oo < 4; ++oo) acc[oo] = swb[grp * 4 + oo];
#pragma unroll
        for (int i = 0; i < 32; ++i) {
            float yv = ysh[i * 17 + n16];
#pragma unroll
            for (int oo = 0; oo < 4; ++oo)
                acc[oo] += WwT[i * 65 + grp * 4 + oo] * yv;
        }
        float* op = out + ((size_t)b * CIN + grp * 4) * BN + nc2 * 16 + n16;
#pragma unroll
        for (int oo = 0; oo < 4; ++oo) op[(size_t)oo * BN] = acc[oo] + xr[oo];
    }
}

// ---------------------------------------------------------------------------
extern "C" void kernel_launch(void* const* d_in, const int* in_sizes, int n_in,
                              void* d_out, int out_size, void* d_ws, size_t ws_size,
                              hipStream_t stream)
{
    const float* x    = (const float*)d_in[0];
    const float* g_w  = (const float*)d_in[1];
    const float* g_b  = (const float*)d_in[2];
    const float* th_w = (const float*)d_in[3];
    const float* th_b = (const float*)d_in[4];
    const float* ph_w = (const float*)d_in[5];
    const float* ph_b = (const float*)d_in[6];
    const float* W_w  = (const float*)d_in[7];
    const float* W_b  = (const float*)d_in[8];
    float* out = (float*)d_out;

    char* ws = (char*)d_ws;
    unsigned short* qT = (unsigned short*)(ws);                  // 1,179,648 B
    unsigned short* kT = (unsigned short*)(ws + 1179648);        // 1,179,648 B
    unsigned short* vv = (unsigned short*)(ws + 2359296);        // 1,179,648 B
    float* pacc = (float*)(ws + 3538944);    // 2*4*288*1024*4 = 9,437,184 B
    float* pl   = (float*)(ws + 12976128);   // 2*4*288*32*4   =   294,912 B

    dim3 g1(BN / 256, 8, NB);
    qkv_kernel<<<g1, 256, 0, stream>>>(x, g_w, g_b, th_w, th_b, ph_w, ph_b,
                                       qT, kT, vv);
    dim3 g2(NCHUNK, MC, NB);
    attn_partial<<<g2, 256, 0, stream>>>(qT, kT, vv, pacc, pl);
    dim3 g3(NCHUNK * 2, NB);
    combine_outconv<<<g3, 256, 0, stream>>>(pacc, pl, W_w, W_b, x, out);
}